// Round 3
// baseline (1824.417 us; speedup 1.0000x reference)
//
#include <hip/hip_runtime.h>

#define N_NODES 100000
#define N_EDGES 1600000
#define N_GRAPHS 256
#define NODE_F 92
#define EDGE_F 41
#define HID 64

typedef float f2 __attribute__((ext_vector_type(2)));
typedef float f4 __attribute__((ext_vector_type(4)));

static __device__ __forceinline__ f2 pk_fma(f2 a, f2 b, f2 c) {
    return __builtin_elementwise_fma(a, b, c);  // -> v_pk_fma_f32 on gfx950
}

// ---------------------------------------------------------------------------
// K1: h = relu(x @ emb_W + emb_b)   [N,92]@[92,64]; one wave/node, lane=chan.
// x rows are 368B (16B-aligned) and wave-uniform -> s_load_dwordx4.
// Weights staged transposed in LDS: sT[(k/4)*256 + lane*4 + (k%3)] so each
// lane does one ds_read_b128 per 4 k's.
// ---------------------------------------------------------------------------
__global__ __launch_bounds__(256) void k_embed(const float* __restrict__ x,
                                               const float* __restrict__ W,
                                               const float* __restrict__ b,
                                               float* __restrict__ h) {
    __shared__ float sT[23 * 256];  // 23.5 KB (92 = 23*4)
    for (int i = threadIdx.x; i < 23 * 256; i += 256) {
        const int kq = i >> 8, rem = i & 255, ln = rem >> 2, kk = rem & 3;
        sT[i] = W[(4 * kq + kk) * HID + ln];
    }
    __syncthreads();
    const int lane = threadIdx.x & 63;
    const int wid  = threadIdx.x >> 6;
    const int nW   = gridDim.x * 4;
    const float bias = b[lane];
    for (int n = blockIdx.x * 4 + wid; n < N_NODES; n += nW) {
        const float* xr = x + (size_t)n * NODE_F;
        float acc = bias;
#pragma unroll
        for (int k0 = 0; k0 < NODE_F; k0 += 4) {
            const f4 xv = *(const f4*)&xr[k0];
            const f4 wv = *(const f4*)&sT[(k0 >> 2) * 256 + 4 * lane];
            acc = fmaf(xv.x, wv.x, acc);
            acc = fmaf(xv.y, wv.y, acc);
            acc = fmaf(xv.z, wv.z, acc);
            acc = fmaf(xv.w, wv.w, acc);
        }
        h[(size_t)n * HID + lane] = fmaxf(acc, 0.f);
    }
}

// ---------------------------------------------------------------------------
// K2 (per layer): node precompute.  For node n, channel c (=lane):
//   D[n][2c+0] = h[n] . Wf[0:64,c]     D[n][2c+1] = h[n] . Ws[0:64,c]
//   S[n][2c+0] = h[n] . Wf[64:128,c]   S[n][2c+1] = h[n] . Ws[64:128,c]
// LDS row k, lane c: sW[k*256+4c..+3] = {Wf[k][c],Ws[k][c],Wf[64+k][c],Ws[64+k][c]}
// -> one ds_read_b128 per (k,lane).  h-row loads are wave-uniform -> s_load.
// RELU_IN=1: apply relu to input on the fly and rewrite own rows in place
// (each node row is owned by exactly one wave; reads precede writes).
// ---------------------------------------------------------------------------
template <int RELU_IN>
__global__ __launch_bounds__(256) void k_node_pre(const float* hin,
                                                  float* hout,
                                                  const float* __restrict__ Wf,
                                                  const float* __restrict__ Ws,
                                                  float* __restrict__ D,
                                                  float* __restrict__ S) {
    __shared__ float sW[64 * 256];  // 64 KB -> 2 blocks/CU
    for (int i = threadIdx.x; i < 64 * 256; i += 256) {
        const int k = i >> 8, j = i & 255, c = j >> 2, r = j & 3;
        float v;
        if (r == 0)      v = Wf[k * HID + c];
        else if (r == 1) v = Ws[k * HID + c];
        else if (r == 2) v = Wf[(64 + k) * HID + c];
        else             v = Ws[(64 + k) * HID + c];
        sW[i] = v;
    }
    __syncthreads();
    const int lane = threadIdx.x & 63;
    const int wid  = threadIdx.x >> 6;
    const int wave = blockIdx.x * 4 + wid;
    const int nW   = gridDim.x * 4;
    // 100000 % 8 == 0 -> every 8-node chunk is full
    for (int base = wave * 8; base < N_NODES; base += nW * 8) {
        f2 accD[8] = {};
        f2 accS[8] = {};
        for (int k0 = 0; k0 < HID; k0 += 4) {
            f4 wv[4];
#pragma unroll
            for (int kk = 0; kk < 4; ++kk)
                wv[kk] = *(const f4*)&sW[(k0 + kk) * 256 + 4 * lane];
#pragma unroll
            for (int m = 0; m < 8; ++m) {
                f4 hv = *(const f4*)&hin[(size_t)(base + m) * HID + k0];
                if (RELU_IN) {
                    hv.x = fmaxf(hv.x, 0.f); hv.y = fmaxf(hv.y, 0.f);
                    hv.z = fmaxf(hv.z, 0.f); hv.w = fmaxf(hv.w, 0.f);
                }
#pragma unroll
                for (int kk = 0; kk < 4; ++kk) {
                    const f2 ev2 = {hv[kk], hv[kk]};
                    const f2 lo = __builtin_shufflevector(wv[kk], wv[kk], 0, 1);
                    const f2 hi = __builtin_shufflevector(wv[kk], wv[kk], 2, 3);
                    accD[m] = pk_fma(ev2, lo, accD[m]);
                    accS[m] = pk_fma(ev2, hi, accS[m]);
                }
            }
        }
#pragma unroll
        for (int m = 0; m < 8; ++m) {
            const size_t n = base + m;
            *(f2*)&D[n * 128 + 2 * lane] = accD[m];
            *(f2*)&S[n * 128 + 2 * lane] = accS[m];
            if (RELU_IN) hout[n * HID + lane] = fmaxf(hin[n * HID + lane], 0.f);
        }
    }
}

// ---------------------------------------------------------------------------
// K3 (per layer): edge kernel, 2 edges per wave iteration for ILP.
// lane = channel.  Per edge:
//   (f,s) = bias + D[dst][2c..] + S[src][2c..] + sum_k e_k * (Wf,Ws)[128+k][c]
//   msg = sigmoid(f)*softplus(s);  agg[dst][c] += msg  (hw fp32 atomic)
// Edge rows are wave-uniform -> scalar (s_load) reads; 41x{Wf,Ws} columns
// live in 82 VGPRs for the whole kernel.
// ---------------------------------------------------------------------------
__global__ __launch_bounds__(256) void k_edge(const int* __restrict__ ei,
                                              const float* __restrict__ ea,
                                              const float* __restrict__ D,
                                              const float* __restrict__ S,
                                              const float* __restrict__ Wf,
                                              const float* __restrict__ Ws,
                                              const float* __restrict__ bf,
                                              const float* __restrict__ bs,
                                              float* __restrict__ agg) {
    const int lane = threadIdx.x & 63;
    f2 w[EDGE_F];
#pragma unroll
    for (int k = 0; k < EDGE_F; ++k)
        w[k] = (f2){Wf[(128 + k) * HID + lane], Ws[(128 + k) * HID + lane]};
    const f2 bias = {bf[lane], bs[lane]};
    const int wave = blockIdx.x * 4 + (threadIdx.x >> 6);
    const int nW   = gridDim.x * 4;
    // N_EDGES even and eA always even -> eB=eA+1 always valid
    for (int e0 = wave * 2; e0 < N_EDGES; e0 += nW * 2) {
        const int eA = __builtin_amdgcn_readfirstlane(e0);
        const int eB = eA + 1;
        const int srcA = __builtin_amdgcn_readfirstlane(ei[eA]);
        const int dstA = __builtin_amdgcn_readfirstlane(ei[N_EDGES + eA]);
        const int srcB = __builtin_amdgcn_readfirstlane(ei[eB]);
        const int dstB = __builtin_amdgcn_readfirstlane(ei[N_EDGES + eB]);
        const float* erA = ea + (size_t)eA * EDGE_F;
        const float* erB = ea + (size_t)eB * EDGE_F;
        // four independent FMA chains (2 edges x even/odd k)
        f2 a0 = bias + *(const f2*)&D[(size_t)dstA * 128 + 2 * lane];
        f2 a1 = *(const f2*)&S[(size_t)srcA * 128 + 2 * lane];
        f2 b0 = bias + *(const f2*)&D[(size_t)dstB * 128 + 2 * lane];
        f2 b1 = *(const f2*)&S[(size_t)srcB * 128 + 2 * lane];
#pragma unroll
        for (int k = 0; k + 1 < EDGE_F; k += 2) {
            const float ea0 = erA[k], ea1 = erA[k + 1];
            const float eb0 = erB[k], eb1 = erB[k + 1];
            a0 = pk_fma((f2){ea0, ea0}, w[k], a0);
            b0 = pk_fma((f2){eb0, eb0}, w[k], b0);
            a1 = pk_fma((f2){ea1, ea1}, w[k + 1], a1);
            b1 = pk_fma((f2){eb1, eb1}, w[k + 1], b1);
        }
        {   // tail k = 40
            const float ea0 = erA[EDGE_F - 1], eb0 = erB[EDGE_F - 1];
            a0 = pk_fma((f2){ea0, ea0}, w[EDGE_F - 1], a0);
            b0 = pk_fma((f2){eb0, eb0}, w[EDGE_F - 1], b0);
        }
        const f2 fsA = a0 + a1;
        const f2 fsB = b0 + b1;
        const float gateA = __builtin_amdgcn_rcpf(1.f + __expf(-fsA.x));
        const float spA   = fmaxf(fsA.y, 0.f) + __logf(1.f + __expf(-fabsf(fsA.y)));
        const float gateB = __builtin_amdgcn_rcpf(1.f + __expf(-fsB.x));
        const float spB   = fmaxf(fsB.y, 0.f) + __logf(1.f + __expf(-fabsf(fsB.y)));
        unsafeAtomicAdd(&agg[(size_t)dstA * HID + lane], gateA * spA);
        unsafeAtomicAdd(&agg[(size_t)dstB * HID + lane], gateB * spB);
    }
}

// ---------------------------------------------------------------------------
// K5: pooled sums + counts; relu applied on the fly (h2 = relu(agg)).
// batch sorted -> run-length accumulate per wave, flush on graph change.
// ---------------------------------------------------------------------------
__global__ __launch_bounds__(256) void k_pool(const float* __restrict__ agg,
                                              const int* __restrict__ batch,
                                              float* __restrict__ psum,
                                              float* __restrict__ pcnt) {
    const int lane = threadIdx.x & 63;
    const int wid  = threadIdx.x >> 6;
    const int wave = blockIdx.x * 4 + wid;
    const int nW   = gridDim.x * 4;
    const int chunk = (N_NODES + nW - 1) / nW;
    const int n0 = wave * chunk;
    if (n0 >= N_NODES) return;
    const int n1 = min(n0 + chunk, N_NODES);
    float acc = 0.f;
    int cur = batch[n0];
    int run = 0;
    for (int n = n0; n < n1; ++n) {
        const int g = batch[n];
        if (g != cur) {
            unsafeAtomicAdd(&psum[(size_t)cur * HID + lane], acc);
            if (lane == 0) unsafeAtomicAdd(&pcnt[cur], (float)run);
            acc = 0.f; run = 0; cur = g;
        }
        acc += fmaxf(agg[(size_t)n * HID + lane], 0.f);
        ++run;
    }
    unsafeAtomicAdd(&psum[(size_t)cur * HID + lane], acc);
    if (lane == 0) unsafeAtomicAdd(&pcnt[cur], (float)run);
}

// ---------------------------------------------------------------------------
// K6: head.  One thread per graph (256 threads, 1 block).
// ---------------------------------------------------------------------------
__global__ __launch_bounds__(256) void k_head(const float* __restrict__ psum,
                                              const float* __restrict__ pcnt,
                                              const float* __restrict__ l1W,
                                              const float* __restrict__ l1b,
                                              const float* __restrict__ l2W,
                                              const float* __restrict__ l2b,
                                              float* __restrict__ out) {
    const int g = threadIdx.x;
    const float inv = 1.f / fmaxf(pcnt[g], 1.f);
    float hid[32];
#pragma unroll
    for (int j = 0; j < 32; ++j) hid[j] = l1b[j];
    for (int c = 0; c < HID; ++c) {
        const float pv = psum[(size_t)g * HID + c] * inv;
#pragma unroll
        for (int j = 0; j < 32; ++j) hid[j] = fmaf(pv, l1W[c * 32 + j], hid[j]);
    }
#pragma unroll
    for (int j = 0; j < 32; ++j) hid[j] = fmaxf(hid[j], 0.f);
#pragma unroll
    for (int k = 0; k < 2; ++k) {
        float a = l2b[k];
#pragma unroll
        for (int j = 0; j < 32; ++j) a = fmaf(hid[j], l2W[j * 2 + k], a);
        out[g * 2 + k] = a;
    }
}

// ---------------------------------------------------------------------------
extern "C" void kernel_launch(void* const* d_in, const int* in_sizes, int n_in,
                              void* d_out, int out_size, void* d_ws, size_t ws_size,
                              hipStream_t stream) {
    const float* x     = (const float*)d_in[0];
    const int*   ei    = (const int*)d_in[1];
    const float* ea    = (const float*)d_in[2];
    const int*   batch = (const int*)d_in[3];
    const float* embW  = (const float*)d_in[4];
    const float* embb  = (const float*)d_in[5];
    const float* c1Wf  = (const float*)d_in[6];
    const float* c1bf  = (const float*)d_in[7];
    const float* c1Ws  = (const float*)d_in[8];
    const float* c1bs  = (const float*)d_in[9];
    const float* c2Wf  = (const float*)d_in[10];
    const float* c2bf  = (const float*)d_in[11];
    const float* c2Ws  = (const float*)d_in[12];
    const float* c2bs  = (const float*)d_in[13];
    const float* l1W   = (const float*)d_in[14];
    const float* l1b   = (const float*)d_in[15];
    const float* l2W   = (const float*)d_in[16];
    const float* l2b   = (const float*)d_in[17];
    float* out = (float*)d_out;

    char* w = (char*)d_ws;
    float* A    = (float*)w; w += (size_t)N_NODES * HID * sizeof(float);  // h/agg (residual in place)
    float* D    = (float*)w; w += (size_t)N_NODES * 128 * sizeof(float);
    float* S    = (float*)w; w += (size_t)N_NODES * 128 * sizeof(float);
    float* psum = (float*)w; w += (size_t)N_GRAPHS * HID * sizeof(float);
    float* pcnt = (float*)w; w += (size_t)N_GRAPHS * sizeof(float);

    hipMemsetAsync(psum, 0, (size_t)(N_GRAPHS * HID + N_GRAPHS) * sizeof(float), stream);

    k_embed<<<1024, 256, 0, stream>>>(x, embW, embb, A);

    // ---- CGConv layer 1 (A holds relu'd h; edges add messages in place) ----
    k_node_pre<0><<<1024, 256, 0, stream>>>(A, A, c1Wf, c1Ws, D, S);
    k_edge<<<2048, 256, 0, stream>>>(ei, ea, D, S, c1Wf, c1Ws, c1bf, c1bs, A);

    // ---- CGConv layer 2 (relu fused into precompute, in-place) ----
    k_node_pre<1><<<1024, 256, 0, stream>>>(A, A, c2Wf, c2Ws, D, S);
    k_edge<<<2048, 256, 0, stream>>>(ei, ea, D, S, c2Wf, c2Ws, c2bf, c2bs, A);

    // ---- pool (relu fused) + head ----
    k_pool<<<512, 256, 0, stream>>>(A, batch, psum, pcnt);
    k_head<<<1, 256, 0, stream>>>(psum, pcnt, l1W, l1b, l2W, l2b, out);
}